// Round 4
// baseline (1845.244 us; speedup 1.0000x reference)
//
#include <hip/hip_runtime.h>

#define IN_DIM 128
#define HID_DIM 256
#define OUT_DIM 128
#define KHOPS 10

// ---------------- CSR build ----------------

__global__ void count_init(int* __restrict__ cnt, int* __restrict__ fill, int N) {
    int i = blockIdx.x * blockDim.x + threadIdx.x;
    if (i < N) { cnt[i] = 0; fill[i] = 0; }
}

__global__ void count_edges(const int* __restrict__ dst, int* __restrict__ cnt, int E) {
    int e = blockIdx.x * blockDim.x + threadIdx.x;
    if (e < E) atomicAdd(&cnt[dst[e]], 1);
}

__global__ void norm_kernel(const int* __restrict__ cnt, float* __restrict__ norm, int N) {
    int i = blockIdx.x * blockDim.x + threadIdx.x;
    if (i < N) {
        float deg = (float)(cnt[i] + 1);   // +1 self loop, always >= 1
        norm[i] = rsqrtf(deg);
    }
}

__global__ void scan_block(const int* __restrict__ cnt, int* __restrict__ row_ptr,
                           int* __restrict__ bsum, int N) {
    __shared__ int s[256];
    int tid = threadIdx.x;
    int gid = blockIdx.x * 256 + tid;
    int v = (gid < N) ? cnt[gid] : 0;
    s[tid] = v;
    __syncthreads();
    for (int off = 1; off < 256; off <<= 1) {
        int t = (tid >= off) ? s[tid - off] : 0;
        __syncthreads();
        s[tid] += t;
        __syncthreads();
    }
    if (gid < N) row_ptr[gid] = s[tid] - v;   // local exclusive
    if (tid == 255) bsum[blockIdx.x] = s[255];
}

__global__ void scan_top(int* __restrict__ bsum, int nb) {
    __shared__ int s[512];
    int tid = threadIdx.x;
    int v = (tid < nb) ? bsum[tid] : 0;
    s[tid] = v;
    __syncthreads();
    for (int off = 1; off < 512; off <<= 1) {
        int t = (tid >= off) ? s[tid - off] : 0;
        __syncthreads();
        s[tid] += t;
        __syncthreads();
    }
    if (tid < nb) bsum[tid] = s[tid] - v;     // exclusive
}

__global__ void scan_add(int* __restrict__ row_ptr, const int* __restrict__ bsum,
                         int N, int E) {
    int gid = blockIdx.x * 256 + threadIdx.x;
    if (gid < N) row_ptr[gid] += bsum[blockIdx.x];
    if (gid == 0) row_ptr[N] = E;
}

__global__ void fill_csr(const int* __restrict__ src, const int* __restrict__ dst,
                         const int* __restrict__ row_ptr, int* __restrict__ fill,
                         int* __restrict__ col, int E) {
    int e = blockIdx.x * blockDim.x + threadIdx.x;
    if (e < E) {
        int d = dst[e];
        int p = atomicAdd(&fill[d], 1);
        col[row_ptr[d] + p] = src[e];
    }
}

// ---------------- propagation ----------------

// g = norm * h.  init: g0 = norm * feat
__global__ void init_g(const float* __restrict__ feat, const float* __restrict__ norm,
                       float* __restrict__ g, int N) {
    int idx = blockIdx.x * blockDim.x + threadIdx.x;   // one float4 per thread
    int total = N * (IN_DIM / 4);
    if (idx >= total) return;
    int row = idx / (IN_DIM / 4);
    float nr = norm[row];
    float4 v = *(const float4*)(feat + (size_t)idx * 4);
    v.x *= nr; v.y *= nr; v.z *= nr; v.w *= nr;
    *(float4*)(g + (size_t)idx * 4) = v;
}

// one full wave per dst node; lane owns 2 dims (float2), wave covers the 512B row.
// node is wave-uniform (readfirstlane) so row_ptr/col fetches become scalar
// s_loads and gather addresses are SGPR-base + fixed lane offset.
// 4-deep unroll -> 4 outstanding 512B gathers per wave.
// g_out[d] = 0.9*norm[d]^2 * (g_in[d] + sum_{s in N(d)} g_in[s]) + 0.1*norm[d]*feat[d]
__global__ __launch_bounds__(256) void hop_kernel(
    const float* __restrict__ g_in, float* __restrict__ g_out,
    const float* __restrict__ feat, const float* __restrict__ norm,
    const int* __restrict__ row_ptr, const int* __restrict__ col,
    int N) {
    int node = __builtin_amdgcn_readfirstlane(blockIdx.x * 4 + (threadIdx.x >> 6));
    int lane = threadIdx.x & 63;
    if (node >= N) return;
    size_t base = (size_t)node * IN_DIM + lane * 2;
    float2 acc = *(const float2*)(g_in + base);        // self loop
    int beg = row_ptr[node], end = row_ptr[node + 1];  // scalar loads
    int e = beg;
    for (; e + 3 < end; e += 4) {
        int s0 = col[e], s1 = col[e + 1], s2 = col[e + 2], s3 = col[e + 3];
        const float2* p0 = (const float2*)(g_in + (size_t)s0 * IN_DIM) + lane;
        const float2* p1 = (const float2*)(g_in + (size_t)s1 * IN_DIM) + lane;
        const float2* p2 = (const float2*)(g_in + (size_t)s2 * IN_DIM) + lane;
        const float2* p3 = (const float2*)(g_in + (size_t)s3 * IN_DIM) + lane;
        float2 a0 = *p0, a1 = *p1, a2 = *p2, a3 = *p3;
        acc.x += (a0.x + a1.x) + (a2.x + a3.x);
        acc.y += (a0.y + a1.y) + (a2.y + a3.y);
    }
    for (; e < end; ++e) {
        int s0 = col[e];
        const float2* p0 = (const float2*)(g_in + (size_t)s0 * IN_DIM) + lane;
        float2 a0 = *p0;
        acc.x += a0.x;
        acc.y += a0.y;
    }
    float nr = norm[node];
    float c1 = 0.9f * nr * nr;
    float c2 = 0.1f * nr;
    float2 f = *(const float2*)(feat + base);
    float2 o;
    o.x = c1 * acc.x + c2 * f.x;
    o.y = c1 * acc.y + c2 * f.y;
    *(float2*)(g_out + base) = o;
}

// ---------------- fused MLP ----------------
// out = relu(h @ W1 + b1) @ W2 + b2,  h = g / norm
// block: 256 threads, 32 node-rows per block.
// LDS = 16.5KB (Ah) + 8.7KB (Hc) = 25.2KB -> 6 blocks/CU (24 waves = 75% occ).

__global__ __launch_bounds__(256) void mlp_fused(
    const float* __restrict__ g, const float* __restrict__ norm,
    const float* __restrict__ W1, const float* __restrict__ b1,
    const float* __restrict__ W2, const float* __restrict__ b2,
    float* __restrict__ out, int N)
{
    __shared__ float Ah[32][IN_DIM + 1];    // 16512 B
    __shared__ float Hc[32][68];            // 8704 B, one 64-col hid chunk
    int tid  = threadIdx.x;
    int row0 = blockIdx.x * 32;

    // load A tile: h = g * (1/norm)
    for (int i = tid; i < 32 * (IN_DIM / 4); i += 256) {
        int r = i >> 5;            // IN_DIM/4 = 32 float4 per row
        int c = (i & 31) << 2;
        int row = row0 + r;
        float4 v = {0.f, 0.f, 0.f, 0.f};
        if (row < N) {
            v = *(const float4*)(g + (size_t)row * IN_DIM + c);
            float inv = 1.0f / norm[row];
            v.x *= inv; v.y *= inv; v.z *= inv; v.w *= inv;
        }
        Ah[r][c + 0] = v.x; Ah[r][c + 1] = v.y; Ah[r][c + 2] = v.z; Ah[r][c + 3] = v.w;
    }
    __syncthreads();

    int ty = tid >> 4;     // 0..15 -> 2 rows each
    int tx = tid & 15;     // 0..15
    int cb2 = tx * 8;

    float acc2[2][8];
    #pragma unroll
    for (int i = 0; i < 2; ++i)
        #pragma unroll
        for (int j = 0; j < 8; ++j) acc2[i][j] = 0.f;

    for (int ch = 0; ch < 4; ++ch) {
        // ---- GEMM1 chunk: Hc = relu(Ah @ W1[:, ch*64 .. +64] + b1) ----
        int colbase = ch * 64 + tx * 4;
        float acc[2][4];
        #pragma unroll
        for (int i = 0; i < 2; ++i)
            #pragma unroll
            for (int j = 0; j < 4; ++j) acc[i][j] = 0.f;

        for (int k = 0; k < IN_DIM; ++k) {
            float4 b = *(const float4*)(W1 + (size_t)k * HID_DIM + colbase);
            #pragma unroll
            for (int i = 0; i < 2; ++i) {
                float a = Ah[ty * 2 + i][k];
                acc[i][0] += a * b.x;
                acc[i][1] += a * b.y;
                acc[i][2] += a * b.z;
                acc[i][3] += a * b.w;
            }
        }
        float4 bias = *(const float4*)(b1 + ch * 64 + tx * 4);
        #pragma unroll
        for (int i = 0; i < 2; ++i) {
            float r0 = acc[i][0] + bias.x;
            float r1 = acc[i][1] + bias.y;
            float r2 = acc[i][2] + bias.z;
            float r3 = acc[i][3] + bias.w;
            Hc[ty * 2 + i][tx * 4 + 0] = r0 > 0.f ? r0 : 0.f;
            Hc[ty * 2 + i][tx * 4 + 1] = r1 > 0.f ? r1 : 0.f;
            Hc[ty * 2 + i][tx * 4 + 2] = r2 > 0.f ? r2 : 0.f;
            Hc[ty * 2 + i][tx * 4 + 3] = r3 > 0.f ? r3 : 0.f;
        }
        __syncthreads();

        // ---- GEMM2 partial: acc2 += Hc @ W2[ch*64 .. +64, :] ----
        for (int k2 = 0; k2 < 64; ++k2) {
            int k = ch * 64 + k2;
            float4 blo = *(const float4*)(W2 + (size_t)k * OUT_DIM + cb2);
            float4 bhi = *(const float4*)(W2 + (size_t)k * OUT_DIM + cb2 + 4);
            #pragma unroll
            for (int i = 0; i < 2; ++i) {
                float a = Hc[ty * 2 + i][k2];
                acc2[i][0] += a * blo.x;
                acc2[i][1] += a * blo.y;
                acc2[i][2] += a * blo.z;
                acc2[i][3] += a * blo.w;
                acc2[i][4] += a * bhi.x;
                acc2[i][5] += a * bhi.y;
                acc2[i][6] += a * bhi.z;
                acc2[i][7] += a * bhi.w;
            }
        }
        __syncthreads();   // protect Hc before next chunk's writes
    }

    float4 b2lo = *(const float4*)(b2 + cb2);
    float4 b2hi = *(const float4*)(b2 + cb2 + 4);
    #pragma unroll
    for (int i = 0; i < 2; ++i) {
        int row = row0 + ty * 2 + i;
        if (row < N) {
            float4 olo, ohi;
            olo.x = acc2[i][0] + b2lo.x;
            olo.y = acc2[i][1] + b2lo.y;
            olo.z = acc2[i][2] + b2lo.z;
            olo.w = acc2[i][3] + b2lo.w;
            ohi.x = acc2[i][4] + b2hi.x;
            ohi.y = acc2[i][5] + b2hi.y;
            ohi.z = acc2[i][6] + b2hi.z;
            ohi.w = acc2[i][7] + b2hi.w;
            *(float4*)(out + (size_t)row * OUT_DIM + cb2)     = olo;
            *(float4*)(out + (size_t)row * OUT_DIM + cb2 + 4) = ohi;
        }
    }
}

// ---------------- launch ----------------

extern "C" void kernel_launch(void* const* d_in, const int* in_sizes, int n_in,
                              void* d_out, int out_size, void* d_ws, size_t ws_size,
                              hipStream_t stream) {
    const float* feat = (const float*)d_in[0];
    const float* W1   = (const float*)d_in[1];
    const float* b1   = (const float*)d_in[2];
    const float* W2   = (const float*)d_in[3];
    const float* b2   = (const float*)d_in[4];
    const int*   src  = (const int*)d_in[5];
    const int*   dst  = (const int*)d_in[6];
    float* out = (float*)d_out;

    int N = in_sizes[0] / IN_DIM;     // 100000
    int E = in_sizes[5];              // 1600000

    // workspace carve (256B aligned)
    size_t off = 0;
    auto carve = [&](size_t bytes) -> void* {
        void* p = (char*)d_ws + off;
        off += (bytes + 255) & ~(size_t)255;
        return p;
    };
    float* norm    = (float*)carve((size_t)N * 4);
    int*   cnt     = (int*)carve((size_t)N * 4);
    int*   row_ptr = (int*)carve((size_t)(N + 1) * 4);
    int*   fill    = (int*)carve((size_t)N * 4);
    int*   bsum    = (int*)carve(512 * 4);
    int*   col     = (int*)carve((size_t)E * 4);
    float* gws     = (float*)carve((size_t)N * IN_DIM * 4);
    (void)ws_size;

    int nbN = (N + 255) / 256;        // 391
    int nbE = (E + 255) / 256;        // 6250

    count_init<<<nbN, 256, 0, stream>>>(cnt, fill, N);
    count_edges<<<nbE, 256, 0, stream>>>(dst, cnt, E);
    norm_kernel<<<nbN, 256, 0, stream>>>(cnt, norm, N);
    scan_block<<<nbN, 256, 0, stream>>>(cnt, row_ptr, bsum, N);
    scan_top<<<1, 512, 0, stream>>>(bsum, nbN);
    scan_add<<<nbN, 256, 0, stream>>>(row_ptr, bsum, N, E);
    fill_csr<<<nbE, 256, 0, stream>>>(src, dst, row_ptr, fill, col, E);

    int nbG = (N * (IN_DIM / 4) + 255) / 256;
    init_g<<<nbG, 256, 0, stream>>>(feat, norm, gws, N);

    // one wave per node, 4 nodes per block
    int nbHop = (N + 3) / 4;
    for (int t = 0; t < KHOPS; ++t) {
        const float* gi = (t % 2 == 0) ? gws : out;
        float*       go = (t % 2 == 0) ? out : gws;
        hop_kernel<<<nbHop, 256, 0, stream>>>(gi, go, feat, norm, row_ptr, col, N);
    }
    // after 10 hops (even), final g is in gws

    int nbM = (N + 31) / 32;
    mlp_fused<<<nbM, 256, 0, stream>>>(gws, norm, W1, b1, W2, b2, out, N);
}

// Round 5
// 1170.099 us; speedup vs baseline: 1.5770x; 1.5770x over previous
//
#include <hip/hip_runtime.h>

#define IN_DIM 128
#define HID_DIM 256
#define OUT_DIM 128
#define KHOPS 10

// bf16 round-to-nearest-even from fp32
__device__ __forceinline__ unsigned short f2bf(float x) {
    unsigned int b = __float_as_uint(x);
    unsigned int r = (b + 0x7FFFu + ((b >> 16) & 1u)) >> 16;
    return (unsigned short)r;
}
__device__ __forceinline__ unsigned int pack_bf2(float lo, float hi) {
    return (unsigned int)f2bf(lo) | ((unsigned int)f2bf(hi) << 16);
}

// ---------------- CSR build ----------------

__global__ void count_init(int* __restrict__ cnt, int* __restrict__ fill, int N) {
    int i = blockIdx.x * blockDim.x + threadIdx.x;
    if (i < N) { cnt[i] = 0; fill[i] = 0; }
}

__global__ void count_edges(const int* __restrict__ dst, int* __restrict__ cnt, int E) {
    int e = blockIdx.x * blockDim.x + threadIdx.x;
    if (e < E) atomicAdd(&cnt[dst[e]], 1);
}

__global__ void norm_kernel(const int* __restrict__ cnt, float* __restrict__ norm, int N) {
    int i = blockIdx.x * blockDim.x + threadIdx.x;
    if (i < N) {
        float deg = (float)(cnt[i] + 1);   // +1 self loop, always >= 1
        norm[i] = rsqrtf(deg);
    }
}

__global__ void scan_block(const int* __restrict__ cnt, int* __restrict__ row_ptr,
                           int* __restrict__ bsum, int N) {
    __shared__ int s[256];
    int tid = threadIdx.x;
    int gid = blockIdx.x * 256 + tid;
    int v = (gid < N) ? cnt[gid] : 0;
    s[tid] = v;
    __syncthreads();
    for (int off = 1; off < 256; off <<= 1) {
        int t = (tid >= off) ? s[tid - off] : 0;
        __syncthreads();
        s[tid] += t;
        __syncthreads();
    }
    if (gid < N) row_ptr[gid] = s[tid] - v;   // local exclusive
    if (tid == 255) bsum[blockIdx.x] = s[255];
}

__global__ void scan_top(int* __restrict__ bsum, int nb) {
    __shared__ int s[512];
    int tid = threadIdx.x;
    int v = (tid < nb) ? bsum[tid] : 0;
    s[tid] = v;
    __syncthreads();
    for (int off = 1; off < 512; off <<= 1) {
        int t = (tid >= off) ? s[tid - off] : 0;
        __syncthreads();
        s[tid] += t;
        __syncthreads();
    }
    if (tid < nb) bsum[tid] = s[tid] - v;     // exclusive
}

__global__ void scan_add(int* __restrict__ row_ptr, const int* __restrict__ bsum,
                         int N, int E) {
    int gid = blockIdx.x * 256 + threadIdx.x;
    if (gid < N) row_ptr[gid] += bsum[blockIdx.x];
    if (gid == 0) row_ptr[N] = E;
}

__global__ void fill_csr(const int* __restrict__ src, const int* __restrict__ dst,
                         const int* __restrict__ row_ptr, int* __restrict__ fill,
                         int* __restrict__ col, int E) {
    int e = blockIdx.x * blockDim.x + threadIdx.x;
    if (e < E) {
        int d = dst[e];
        int p = atomicAdd(&fill[d], 1);
        col[row_ptr[d] + p] = src[e];
    }
}

// ---------------- propagation ----------------
// g = norm * h (fp32 master) + bf16 shadow for the gather path.

__global__ void init_g(const float* __restrict__ feat, const float* __restrict__ norm,
                       float* __restrict__ g, unsigned int* __restrict__ sh, int N) {
    int idx = blockIdx.x * blockDim.x + threadIdx.x;   // one float4 per thread
    int total = N * (IN_DIM / 4);
    if (idx >= total) return;
    int row = idx / (IN_DIM / 4);
    float nr = norm[row];
    float4 v = *(const float4*)(feat + (size_t)idx * 4);
    v.x *= nr; v.y *= nr; v.z *= nr; v.w *= nr;
    *(float4*)(g + (size_t)idx * 4) = v;
    uint2 p;
    p.x = pack_bf2(v.x, v.y);
    p.y = pack_bf2(v.z, v.w);
    *(uint2*)(sh + (size_t)idx * 2) = p;     // 2 uints per float4
}

// one full wave per dst node; lane owns dims (2l, 2l+1).
// gather reads the bf16 shadow (256B/row); self/feat/state stay fp32.
// g_out[d] = 0.9*norm[d]^2 * (g_in[d] + sum_{s in N(d)} sh_in[s]) + 0.1*norm[d]*feat[d]
__global__ __launch_bounds__(256) void hop_kernel(
    const float* __restrict__ g_in, float* __restrict__ g_out,
    const unsigned int* __restrict__ sh_in, unsigned int* __restrict__ sh_out,
    const float* __restrict__ feat, const float* __restrict__ norm,
    const int* __restrict__ row_ptr, const int* __restrict__ col,
    int N) {
    int node = __builtin_amdgcn_readfirstlane(blockIdx.x * 4 + (threadIdx.x >> 6));
    int lane = threadIdx.x & 63;
    if (node >= N) return;
    size_t base = (size_t)node * IN_DIM + lane * 2;
    float2 acc = *(const float2*)(g_in + base);        // self loop (fp32)
    int beg = row_ptr[node], end = row_ptr[node + 1];  // scalar loads
    int e = beg;
    for (; e + 7 < end; e += 8) {
        int s0 = col[e],     s1 = col[e + 1], s2 = col[e + 2], s3 = col[e + 3];
        int s4 = col[e + 4], s5 = col[e + 5], s6 = col[e + 6], s7 = col[e + 7];
        unsigned int u0 = sh_in[(size_t)s0 * 64 + lane];
        unsigned int u1 = sh_in[(size_t)s1 * 64 + lane];
        unsigned int u2 = sh_in[(size_t)s2 * 64 + lane];
        unsigned int u3 = sh_in[(size_t)s3 * 64 + lane];
        unsigned int u4 = sh_in[(size_t)s4 * 64 + lane];
        unsigned int u5 = sh_in[(size_t)s5 * 64 + lane];
        unsigned int u6 = sh_in[(size_t)s6 * 64 + lane];
        unsigned int u7 = sh_in[(size_t)s7 * 64 + lane];
        acc.x += __uint_as_float(u0 << 16) + __uint_as_float(u1 << 16)
               + __uint_as_float(u2 << 16) + __uint_as_float(u3 << 16)
               + __uint_as_float(u4 << 16) + __uint_as_float(u5 << 16)
               + __uint_as_float(u6 << 16) + __uint_as_float(u7 << 16);
        acc.y += __uint_as_float(u0 & 0xFFFF0000u) + __uint_as_float(u1 & 0xFFFF0000u)
               + __uint_as_float(u2 & 0xFFFF0000u) + __uint_as_float(u3 & 0xFFFF0000u)
               + __uint_as_float(u4 & 0xFFFF0000u) + __uint_as_float(u5 & 0xFFFF0000u)
               + __uint_as_float(u6 & 0xFFFF0000u) + __uint_as_float(u7 & 0xFFFF0000u);
    }
    for (; e < end; ++e) {
        unsigned int u = sh_in[(size_t)col[e] * 64 + lane];
        acc.x += __uint_as_float(u << 16);
        acc.y += __uint_as_float(u & 0xFFFF0000u);
    }
    float nr = norm[node];
    float c1 = 0.9f * nr * nr;
    float c2 = 0.1f * nr;
    float2 f = *(const float2*)(feat + base);
    float2 o;
    o.x = c1 * acc.x + c2 * f.x;
    o.y = c1 * acc.y + c2 * f.y;
    *(float2*)(g_out + base) = o;
    sh_out[(size_t)node * 64 + lane] = pack_bf2(o.x, o.y);
}

// ---------------- fused MLP ----------------
// out = relu(h @ W1 + b1) @ W2 + b2,  h = g / norm
// 64-row tile (R2 config: 265us, bound by L1/L2 weight re-reads; smaller
// tiles double aggregate weight traffic and regress).

__global__ __launch_bounds__(256) void mlp_fused(
    const float* __restrict__ g, const float* __restrict__ norm,
    const float* __restrict__ W1, const float* __restrict__ b1,
    const float* __restrict__ W2, const float* __restrict__ b2,
    float* __restrict__ out, int N)
{
    __shared__ float Ah[64][IN_DIM + 1];    // 33024 B
    __shared__ float Hc[64][68];            // 17408 B, one 64-col hid chunk
    int tid  = threadIdx.x;
    int row0 = blockIdx.x * 64;

    // load A tile: h = g * (1/norm)
    for (int i = tid; i < 64 * (IN_DIM / 4); i += 256) {
        int r = i >> 5;            // IN_DIM/4 = 32 float4 per row
        int c = (i & 31) << 2;
        int row = row0 + r;
        float4 v = {0.f, 0.f, 0.f, 0.f};
        if (row < N) {
            v = *(const float4*)(g + (size_t)row * IN_DIM + c);
            float inv = 1.0f / norm[row];
            v.x *= inv; v.y *= inv; v.z *= inv; v.w *= inv;
        }
        Ah[r][c + 0] = v.x; Ah[r][c + 1] = v.y; Ah[r][c + 2] = v.z; Ah[r][c + 3] = v.w;
    }
    __syncthreads();

    int ty = tid >> 4;     // 0..15 -> 4 rows each
    int tx = tid & 15;     // 0..15
    int cb2 = tx * 8;

    float acc2[4][8];
    #pragma unroll
    for (int i = 0; i < 4; ++i)
        #pragma unroll
        for (int j = 0; j < 8; ++j) acc2[i][j] = 0.f;

    for (int ch = 0; ch < 4; ++ch) {
        // ---- GEMM1 chunk: Hc = relu(Ah @ W1[:, ch*64 .. +64] + b1) ----
        int colbase = ch * 64 + tx * 4;
        float acc[4][4];
        #pragma unroll
        for (int i = 0; i < 4; ++i)
            #pragma unroll
            for (int j = 0; j < 4; ++j) acc[i][j] = 0.f;

        for (int k = 0; k < IN_DIM; ++k) {
            float4 b = *(const float4*)(W1 + (size_t)k * HID_DIM + colbase);
            #pragma unroll
            for (int i = 0; i < 4; ++i) {
                float a = Ah[ty * 4 + i][k];
                acc[i][0] += a * b.x;
                acc[i][1] += a * b.y;
                acc[i][2] += a * b.z;
                acc[i][3] += a * b.w;
            }
        }
        float4 bias = *(const float4*)(b1 + ch * 64 + tx * 4);
        #pragma unroll
        for (int i = 0; i < 4; ++i) {
            float r0 = acc[i][0] + bias.x;
            float r1 = acc[i][1] + bias.y;
            float r2 = acc[i][2] + bias.z;
            float r3 = acc[i][3] + bias.w;
            Hc[ty * 4 + i][tx * 4 + 0] = r0 > 0.f ? r0 : 0.f;
            Hc[ty * 4 + i][tx * 4 + 1] = r1 > 0.f ? r1 : 0.f;
            Hc[ty * 4 + i][tx * 4 + 2] = r2 > 0.f ? r2 : 0.f;
            Hc[ty * 4 + i][tx * 4 + 3] = r3 > 0.f ? r3 : 0.f;
        }
        __syncthreads();

        // ---- GEMM2 partial: acc2 += Hc @ W2[ch*64 .. +64, :] ----
        for (int k2 = 0; k2 < 64; ++k2) {
            int k = ch * 64 + k2;
            float4 blo = *(const float4*)(W2 + (size_t)k * OUT_DIM + cb2);
            float4 bhi = *(const float4*)(W2 + (size_t)k * OUT_DIM + cb2 + 4);
            #pragma unroll
            for (int i = 0; i < 4; ++i) {
                float a = Hc[ty * 4 + i][k2];
                acc2[i][0] += a * blo.x;
                acc2[i][1] += a * blo.y;
                acc2[i][2] += a * blo.z;
                acc2[i][3] += a * blo.w;
                acc2[i][4] += a * bhi.x;
                acc2[i][5] += a * bhi.y;
                acc2[i][6] += a * bhi.z;
                acc2[i][7] += a * bhi.w;
            }
        }
        __syncthreads();   // protect Hc before next chunk's writes
    }

    float4 b2lo = *(const float4*)(b2 + cb2);
    float4 b2hi = *(const float4*)(b2 + cb2 + 4);
    #pragma unroll
    for (int i = 0; i < 4; ++i) {
        int row = row0 + ty * 4 + i;
        if (row < N) {
            float4 olo, ohi;
            olo.x = acc2[i][0] + b2lo.x;
            olo.y = acc2[i][1] + b2lo.y;
            olo.z = acc2[i][2] + b2lo.z;
            olo.w = acc2[i][3] + b2lo.w;
            ohi.x = acc2[i][4] + b2hi.x;
            ohi.y = acc2[i][5] + b2hi.y;
            ohi.z = acc2[i][6] + b2hi.z;
            ohi.w = acc2[i][7] + b2hi.w;
            *(float4*)(out + (size_t)row * OUT_DIM + cb2)     = olo;
            *(float4*)(out + (size_t)row * OUT_DIM + cb2 + 4) = ohi;
        }
    }
}

// ---------------- launch ----------------

extern "C" void kernel_launch(void* const* d_in, const int* in_sizes, int n_in,
                              void* d_out, int out_size, void* d_ws, size_t ws_size,
                              hipStream_t stream) {
    const float* feat = (const float*)d_in[0];
    const float* W1   = (const float*)d_in[1];
    const float* b1   = (const float*)d_in[2];
    const float* W2   = (const float*)d_in[3];
    const float* b2   = (const float*)d_in[4];
    const int*   src  = (const int*)d_in[5];
    const int*   dst  = (const int*)d_in[6];
    float* out = (float*)d_out;

    int N = in_sizes[0] / IN_DIM;     // 100000
    int E = in_sizes[5];              // 1600000

    // workspace carve (256B aligned)
    size_t off = 0;
    auto carve = [&](size_t bytes) -> void* {
        void* p = (char*)d_ws + off;
        off += (bytes + 255) & ~(size_t)255;
        return p;
    };
    float* norm    = (float*)carve((size_t)N * 4);
    int*   cnt     = (int*)carve((size_t)N * 4);
    int*   row_ptr = (int*)carve((size_t)(N + 1) * 4);
    int*   fill    = (int*)carve((size_t)N * 4);
    int*   bsum    = (int*)carve(512 * 4);
    int*   col     = (int*)carve((size_t)E * 4);
    float* gws     = (float*)carve((size_t)N * IN_DIM * 4);
    unsigned int* shA = (unsigned int*)carve((size_t)N * 64 * 4);  // bf16 shadow ping
    unsigned int* shB = (unsigned int*)carve((size_t)N * 64 * 4);  // bf16 shadow pong
    (void)ws_size;

    int nbN = (N + 255) / 256;        // 391
    int nbE = (E + 255) / 256;        // 6250

    count_init<<<nbN, 256, 0, stream>>>(cnt, fill, N);
    count_edges<<<nbE, 256, 0, stream>>>(dst, cnt, E);
    norm_kernel<<<nbN, 256, 0, stream>>>(cnt, norm, N);
    scan_block<<<nbN, 256, 0, stream>>>(cnt, row_ptr, bsum, N);
    scan_top<<<1, 512, 0, stream>>>(bsum, nbN);
    scan_add<<<nbN, 256, 0, stream>>>(row_ptr, bsum, N, E);
    fill_csr<<<nbE, 256, 0, stream>>>(src, dst, row_ptr, fill, col, E);

    int nbG = (N * (IN_DIM / 4) + 255) / 256;
    init_g<<<nbG, 256, 0, stream>>>(feat, norm, gws, shA, N);

    // one wave per node, 4 nodes per block
    int nbHop = (N + 3) / 4;
    for (int t = 0; t < KHOPS; ++t) {
        const float*        gi  = (t % 2 == 0) ? gws : out;
        float*              go  = (t % 2 == 0) ? out : gws;
        const unsigned int* si  = (t % 2 == 0) ? shA : shB;
        unsigned int*       so  = (t % 2 == 0) ? shB : shA;
        hop_kernel<<<nbHop, 256, 0, stream>>>(gi, go, si, so, feat, norm, row_ptr, col, N);
    }
    // after 10 hops (even), final fp32 g is in gws

    int nbM = (N + 63) / 64;
    mlp_fused<<<nbM, 256, 0, stream>>>(gws, norm, W1, b1, W2, b2, out, N);
}

// Round 6
// 1037.991 us; speedup vs baseline: 1.7777x; 1.1273x over previous
//
#include <hip/hip_runtime.h>

#define IN_DIM 128
#define HID_DIM 256
#define OUT_DIM 128
#define KHOPS 10

// bf16 round-to-nearest-even from fp32
__device__ __forceinline__ unsigned short f2bf(float x) {
    unsigned int b = __float_as_uint(x);
    unsigned int r = (b + 0x7FFFu + ((b >> 16) & 1u)) >> 16;
    return (unsigned short)r;
}
__device__ __forceinline__ unsigned int pack_bf2(float lo, float hi) {
    return (unsigned int)f2bf(lo) | ((unsigned int)f2bf(hi) << 16);
}
__device__ __forceinline__ float bf_lo(unsigned int u) { return __uint_as_float(u << 16); }
__device__ __forceinline__ float bf_hi(unsigned int u) { return __uint_as_float(u & 0xFFFF0000u); }

// ---------------- CSR build ----------------

__global__ void count_init(int* __restrict__ cnt, int* __restrict__ fill, int N) {
    int i = blockIdx.x * blockDim.x + threadIdx.x;
    if (i < N) { cnt[i] = 0; fill[i] = 0; }
}

__global__ void count_edges(const int* __restrict__ dst, int* __restrict__ cnt, int E) {
    int e = blockIdx.x * blockDim.x + threadIdx.x;
    if (e < E) atomicAdd(&cnt[dst[e]], 1);
}

__global__ void norm_kernel(const int* __restrict__ cnt, float* __restrict__ norm, int N) {
    int i = blockIdx.x * blockDim.x + threadIdx.x;
    if (i < N) {
        float deg = (float)(cnt[i] + 1);   // +1 self loop, always >= 1
        norm[i] = rsqrtf(deg);
    }
}

__global__ void scan_block(const int* __restrict__ cnt, int* __restrict__ row_ptr,
                           int* __restrict__ bsum, int N) {
    __shared__ int s[256];
    int tid = threadIdx.x;
    int gid = blockIdx.x * 256 + tid;
    int v = (gid < N) ? cnt[gid] : 0;
    s[tid] = v;
    __syncthreads();
    for (int off = 1; off < 256; off <<= 1) {
        int t = (tid >= off) ? s[tid - off] : 0;
        __syncthreads();
        s[tid] += t;
        __syncthreads();
    }
    if (gid < N) row_ptr[gid] = s[tid] - v;   // local exclusive
    if (tid == 255) bsum[blockIdx.x] = s[255];
}

__global__ void scan_top(int* __restrict__ bsum, int nb) {
    __shared__ int s[512];
    int tid = threadIdx.x;
    int v = (tid < nb) ? bsum[tid] : 0;
    s[tid] = v;
    __syncthreads();
    for (int off = 1; off < 512; off <<= 1) {
        int t = (tid >= off) ? s[tid - off] : 0;
        __syncthreads();
        s[tid] += t;
        __syncthreads();
    }
    if (tid < nb) bsum[tid] = s[tid] - v;     // exclusive
}

__global__ void scan_add(int* __restrict__ row_ptr, const int* __restrict__ bsum,
                         int N, int E) {
    int gid = blockIdx.x * 256 + threadIdx.x;
    if (gid < N) row_ptr[gid] += bsum[blockIdx.x];
    if (gid == 0) row_ptr[N] = E;
}

__global__ void fill_csr(const int* __restrict__ src, const int* __restrict__ dst,
                         const int* __restrict__ row_ptr, int* __restrict__ fill,
                         int* __restrict__ col, int E) {
    int e = blockIdx.x * blockDim.x + threadIdx.x;
    if (e < E) {
        int d = dst[e];
        int p = atomicAdd(&fill[d], 1);
        col[row_ptr[d] + p] = src[e];
    }
}

// ---------------- propagation ----------------
// State lives ONLY as packed bf16 pairs: sh[node*64 + l] = (g[2l], g[2l+1]).
// ffeat[node*64 + l] = packed bf16 of 0.1*norm*feat (the per-hop additive term).

__global__ void init_g(const float* __restrict__ feat, const float* __restrict__ norm,
                       unsigned int* __restrict__ sh, unsigned int* __restrict__ ffeat,
                       int N) {
    int idx = blockIdx.x * blockDim.x + threadIdx.x;   // one bf16-pair per thread
    int total = N * 64;
    if (idx >= total) return;
    int row = idx >> 6;
    int l   = idx & 63;
    float nr = norm[row];
    float2 f = *(const float2*)(feat + (size_t)row * IN_DIM + l * 2);
    sh[idx]    = pack_bf2(nr * f.x, nr * f.y);
    ffeat[idx] = pack_bf2(0.1f * nr * f.x, 0.1f * nr * f.y);
}

// one full wave per dst node; lane owns dims (2l, 2l+1) as one packed uint.
// sh_out[d] = bf16( 0.9*norm[d]^2 * (sh_in[d] + sum_{s in N(d)} sh_in[s]) + ffeat[d] )
__global__ __launch_bounds__(256) void hop_kernel(
    const unsigned int* __restrict__ sh_in, unsigned int* __restrict__ sh_out,
    const unsigned int* __restrict__ ffeat, const float* __restrict__ norm,
    const int* __restrict__ row_ptr, const int* __restrict__ col,
    int N) {
    int node = __builtin_amdgcn_readfirstlane(blockIdx.x * 4 + (threadIdx.x >> 6));
    int lane = threadIdx.x & 63;
    if (node >= N) return;
    size_t base = (size_t)node * 64 + lane;
    unsigned int uself = sh_in[base];
    float2 acc = { bf_lo(uself), bf_hi(uself) };       // self loop
    int beg = row_ptr[node], end = row_ptr[node + 1];  // scalar loads
    int e = beg;
    for (; e + 7 < end; e += 8) {
        int s0 = col[e],     s1 = col[e + 1], s2 = col[e + 2], s3 = col[e + 3];
        int s4 = col[e + 4], s5 = col[e + 5], s6 = col[e + 6], s7 = col[e + 7];
        unsigned int u0 = sh_in[(size_t)s0 * 64 + lane];
        unsigned int u1 = sh_in[(size_t)s1 * 64 + lane];
        unsigned int u2 = sh_in[(size_t)s2 * 64 + lane];
        unsigned int u3 = sh_in[(size_t)s3 * 64 + lane];
        unsigned int u4 = sh_in[(size_t)s4 * 64 + lane];
        unsigned int u5 = sh_in[(size_t)s5 * 64 + lane];
        unsigned int u6 = sh_in[(size_t)s6 * 64 + lane];
        unsigned int u7 = sh_in[(size_t)s7 * 64 + lane];
        acc.x += (bf_lo(u0) + bf_lo(u1)) + (bf_lo(u2) + bf_lo(u3))
               + (bf_lo(u4) + bf_lo(u5)) + (bf_lo(u6) + bf_lo(u7));
        acc.y += (bf_hi(u0) + bf_hi(u1)) + (bf_hi(u2) + bf_hi(u3))
               + (bf_hi(u4) + bf_hi(u5)) + (bf_hi(u6) + bf_hi(u7));
    }
    for (; e < end; ++e) {
        unsigned int u = sh_in[(size_t)col[e] * 64 + lane];
        acc.x += bf_lo(u);
        acc.y += bf_hi(u);
    }
    float nr = norm[node];
    float c1 = 0.9f * nr * nr;
    unsigned int uff = ffeat[base];
    float ox = c1 * acc.x + bf_lo(uff);
    float oy = c1 * acc.y + bf_hi(uff);
    sh_out[base] = pack_bf2(ox, oy);
}

// ---------------- fused MLP ----------------
// out = relu(h @ W1 + b1) @ W2 + b2,  h = unpack(sh) / norm
// 64-row tile; LDS reads vectorized to ds_read_b128 with k-unroll x4
// (previous version was LDS-pipe bound: ~3K ds_read_b32/wave vs 16K VFMA).

__global__ __launch_bounds__(256) void mlp_fused(
    const unsigned int* __restrict__ sh, const float* __restrict__ norm,
    const float* __restrict__ W1, const float* __restrict__ b1,
    const float* __restrict__ W2, const float* __restrict__ b2,
    float* __restrict__ out, int N)
{
    __shared__ float Ah[64][IN_DIM + 4];    // stride 132 floats: 16B-aligned rows
    __shared__ float Hc[64][68];            // stride 68: 16B-aligned rows
    int tid  = threadIdx.x;
    int row0 = blockIdx.x * 64;

    // load A tile: h = unpack_bf16(sh) * (1/norm); 2048 packed pairs / 256 thr
    for (int i = tid; i < 64 * 32; i += 256) {
        int r = i >> 5;            // 32 uint-pairs (uint2) per row
        int p = i & 31;
        int row = row0 + r;
        float4 v = {0.f, 0.f, 0.f, 0.f};
        if (row < N) {
            uint2 u = *(const uint2*)(sh + (size_t)row * 64 + p * 2);
            float inv = 1.0f / norm[row];
            v.x = bf_lo(u.x) * inv; v.y = bf_hi(u.x) * inv;
            v.z = bf_lo(u.y) * inv; v.w = bf_hi(u.y) * inv;
        }
        *(float4*)&Ah[r][p * 4] = v;
    }
    __syncthreads();

    int ty = tid >> 4;     // 0..15 -> 4 rows each
    int tx = tid & 15;     // 0..15
    int cb2 = tx * 8;

    float acc2[4][8];
    #pragma unroll
    for (int i = 0; i < 4; ++i)
        #pragma unroll
        for (int j = 0; j < 8; ++j) acc2[i][j] = 0.f;

    for (int ch = 0; ch < 4; ++ch) {
        // ---- GEMM1 chunk: Hc = relu(Ah @ W1[:, ch*64 .. +64] + b1) ----
        int colbase = ch * 64 + tx * 4;
        float acc[4][4];
        #pragma unroll
        for (int i = 0; i < 4; ++i)
            #pragma unroll
            for (int j = 0; j < 4; ++j) acc[i][j] = 0.f;

        for (int k = 0; k < IN_DIM; k += 4) {
            float4 w0 = *(const float4*)(W1 + (size_t)(k + 0) * HID_DIM + colbase);
            float4 w1 = *(const float4*)(W1 + (size_t)(k + 1) * HID_DIM + colbase);
            float4 w2 = *(const float4*)(W1 + (size_t)(k + 2) * HID_DIM + colbase);
            float4 w3 = *(const float4*)(W1 + (size_t)(k + 3) * HID_DIM + colbase);
            #pragma unroll
            for (int i = 0; i < 4; ++i) {
                float4 a = *(const float4*)&Ah[ty * 4 + i][k];   // ds_read_b128
                acc[i][0] += a.x * w0.x + a.y * w1.x + a.z * w2.x + a.w * w3.x;
                acc[i][1] += a.x * w0.y + a.y * w1.y + a.z * w2.y + a.w * w3.y;
                acc[i][2] += a.x * w0.z + a.y * w1.z + a.z * w2.z + a.w * w3.z;
                acc[i][3] += a.x * w0.w + a.y * w1.w + a.z * w2.w + a.w * w3.w;
            }
        }
        float4 bias = *(const float4*)(b1 + ch * 64 + tx * 4);
        #pragma unroll
        for (int i = 0; i < 4; ++i) {
            float r0 = acc[i][0] + bias.x;
            float r1 = acc[i][1] + bias.y;
            float r2 = acc[i][2] + bias.z;
            float r3 = acc[i][3] + bias.w;
            float4 hv;
            hv.x = r0 > 0.f ? r0 : 0.f;
            hv.y = r1 > 0.f ? r1 : 0.f;
            hv.z = r2 > 0.f ? r2 : 0.f;
            hv.w = r3 > 0.f ? r3 : 0.f;
            *(float4*)&Hc[ty * 4 + i][tx * 4] = hv;
        }
        __syncthreads();

        // ---- GEMM2 partial: acc2 += Hc @ W2[ch*64 .. +64, :] ----
        for (int k2 = 0; k2 < 64; k2 += 4) {
            int k = ch * 64 + k2;
            float4 b0lo = *(const float4*)(W2 + (size_t)(k + 0) * OUT_DIM + cb2);
            float4 b0hi = *(const float4*)(W2 + (size_t)(k + 0) * OUT_DIM + cb2 + 4);
            float4 b1lo = *(const float4*)(W2 + (size_t)(k + 1) * OUT_DIM + cb2);
            float4 b1hi = *(const float4*)(W2 + (size_t)(k + 1) * OUT_DIM + cb2 + 4);
            float4 b2lo_ = *(const float4*)(W2 + (size_t)(k + 2) * OUT_DIM + cb2);
            float4 b2hi_ = *(const float4*)(W2 + (size_t)(k + 2) * OUT_DIM + cb2 + 4);
            float4 b3lo = *(const float4*)(W2 + (size_t)(k + 3) * OUT_DIM + cb2);
            float4 b3hi = *(const float4*)(W2 + (size_t)(k + 3) * OUT_DIM + cb2 + 4);
            #pragma unroll
            for (int i = 0; i < 4; ++i) {
                float4 a = *(const float4*)&Hc[ty * 4 + i][k2];  // ds_read_b128
                acc2[i][0] += a.x * b0lo.x + a.y * b1lo.x + a.z * b2lo_.x + a.w * b3lo.x;
                acc2[i][1] += a.x * b0lo.y + a.y * b1lo.y + a.z * b2lo_.y + a.w * b3lo.y;
                acc2[i][2] += a.x * b0lo.z + a.y * b1lo.z + a.z * b2lo_.z + a.w * b3lo.z;
                acc2[i][3] += a.x * b0lo.w + a.y * b1lo.w + a.z * b2lo_.w + a.w * b3lo.w;
                acc2[i][4] += a.x * b0hi.x + a.y * b1hi.x + a.z * b2hi_.x + a.w * b3hi.x;
                acc2[i][5] += a.x * b0hi.y + a.y * b1hi.y + a.z * b2hi_.y + a.w * b3hi.y;
                acc2[i][6] += a.x * b0hi.z + a.y * b1hi.z + a.z * b2hi_.z + a.w * b3hi.z;
                acc2[i][7] += a.x * b0hi.w + a.y * b1hi.w + a.z * b2hi_.w + a.w * b3hi.w;
            }
        }
        __syncthreads();   // protect Hc before next chunk's writes
    }

    float4 b2lo = *(const float4*)(b2 + cb2);
    float4 b2hi = *(const float4*)(b2 + cb2 + 4);
    #pragma unroll
    for (int i = 0; i < 4; ++i) {
        int row = row0 + ty * 4 + i;
        if (row < N) {
            float4 olo, ohi;
            olo.x = acc2[i][0] + b2lo.x;
            olo.y = acc2[i][1] + b2lo.y;
            olo.z = acc2[i][2] + b2lo.z;
            olo.w = acc2[i][3] + b2lo.w;
            ohi.x = acc2[i][4] + b2hi.x;
            ohi.y = acc2[i][5] + b2hi.y;
            ohi.z = acc2[i][6] + b2hi.z;
            ohi.w = acc2[i][7] + b2hi.w;
            *(float4*)(out + (size_t)row * OUT_DIM + cb2)     = olo;
            *(float4*)(out + (size_t)row * OUT_DIM + cb2 + 4) = ohi;
        }
    }
}

// ---------------- launch ----------------

extern "C" void kernel_launch(void* const* d_in, const int* in_sizes, int n_in,
                              void* d_out, int out_size, void* d_ws, size_t ws_size,
                              hipStream_t stream) {
    const float* feat = (const float*)d_in[0];
    const float* W1   = (const float*)d_in[1];
    const float* b1   = (const float*)d_in[2];
    const float* W2   = (const float*)d_in[3];
    const float* b2   = (const float*)d_in[4];
    const int*   src  = (const int*)d_in[5];
    const int*   dst  = (const int*)d_in[6];
    float* out = (float*)d_out;

    int N = in_sizes[0] / IN_DIM;     // 100000
    int E = in_sizes[5];              // 1600000

    // workspace carve (256B aligned)
    size_t off = 0;
    auto carve = [&](size_t bytes) -> void* {
        void* p = (char*)d_ws + off;
        off += (bytes + 255) & ~(size_t)255;
        return p;
    };
    float* norm    = (float*)carve((size_t)N * 4);
    int*   cnt     = (int*)carve((size_t)N * 4);
    int*   row_ptr = (int*)carve((size_t)(N + 1) * 4);
    int*   fill    = (int*)carve((size_t)N * 4);
    int*   bsum    = (int*)carve(512 * 4);
    int*   col     = (int*)carve((size_t)E * 4);
    unsigned int* shA   = (unsigned int*)carve((size_t)N * 64 * 4);  // bf16 state ping
    unsigned int* shB   = (unsigned int*)carve((size_t)N * 64 * 4);  // bf16 state pong
    unsigned int* ffeat = (unsigned int*)carve((size_t)N * 64 * 4);  // bf16 0.1*norm*feat
    (void)ws_size;

    int nbN = (N + 255) / 256;        // 391
    int nbE = (E + 255) / 256;        // 6250

    count_init<<<nbN, 256, 0, stream>>>(cnt, fill, N);
    count_edges<<<nbE, 256, 0, stream>>>(dst, cnt, E);
    norm_kernel<<<nbN, 256, 0, stream>>>(cnt, norm, N);
    scan_block<<<nbN, 256, 0, stream>>>(cnt, row_ptr, bsum, N);
    scan_top<<<1, 512, 0, stream>>>(bsum, nbN);
    scan_add<<<nbN, 256, 0, stream>>>(row_ptr, bsum, N, E);
    fill_csr<<<nbE, 256, 0, stream>>>(src, dst, row_ptr, fill, col, E);

    int nbG = ((size_t)N * 64 + 255) / 256;
    init_g<<<nbG, 256, 0, stream>>>(feat, norm, shA, ffeat, N);

    // one wave per node, 4 nodes per block
    int nbHop = (N + 3) / 4;
    for (int t = 0; t < KHOPS; ++t) {
        const unsigned int* si = (t % 2 == 0) ? shA : shB;
        unsigned int*       so = (t % 2 == 0) ? shB : shA;
        hop_kernel<<<nbHop, 256, 0, stream>>>(si, so, ffeat, norm, row_ptr, col, N);
    }
    // after 10 hops (even count), final state is in shA

    int nbM = (N + 63) / 64;
    mlp_fused<<<nbM, 256, 0, stream>>>(shA, norm, W1, b1, W2, b2, out, N);
}

// Round 7
// 885.681 us; speedup vs baseline: 2.0834x; 1.1720x over previous
//
#include <hip/hip_runtime.h>

#define IN_DIM 128
#define HID_DIM 256
#define OUT_DIM 128
#define KHOPS 10

typedef __attribute__((ext_vector_type(8))) short bf16x8;
typedef __attribute__((ext_vector_type(4))) float f32x4;

// bf16 round-to-nearest-even from fp32
__device__ __forceinline__ unsigned short f2bf(float x) {
    unsigned int b = __float_as_uint(x);
    unsigned int r = (b + 0x7FFFu + ((b >> 16) & 1u)) >> 16;
    return (unsigned short)r;
}
__device__ __forceinline__ unsigned int pack_bf2(float lo, float hi) {
    return (unsigned int)f2bf(lo) | ((unsigned int)f2bf(hi) << 16);
}
__device__ __forceinline__ float bf_lo(unsigned int u) { return __uint_as_float(u << 16); }
__device__ __forceinline__ float bf_hi(unsigned int u) { return __uint_as_float(u & 0xFFFF0000u); }

// ---------------- CSR build ----------------

__global__ void count_init(int* __restrict__ cnt, int* __restrict__ fill, int N) {
    int i = blockIdx.x * blockDim.x + threadIdx.x;
    if (i < N) { cnt[i] = 0; fill[i] = 0; }
}

__global__ void count_edges(const int* __restrict__ dst, int* __restrict__ cnt, int E) {
    int e = blockIdx.x * blockDim.x + threadIdx.x;
    if (e < E) atomicAdd(&cnt[dst[e]], 1);
}

__global__ void norm_kernel(const int* __restrict__ cnt, float* __restrict__ norm, int N) {
    int i = blockIdx.x * blockDim.x + threadIdx.x;
    if (i < N) {
        float deg = (float)(cnt[i] + 1);   // +1 self loop, always >= 1
        norm[i] = rsqrtf(deg);
    }
}

__global__ void scan_block(const int* __restrict__ cnt, int* __restrict__ row_ptr,
                           int* __restrict__ bsum, int N) {
    __shared__ int s[256];
    int tid = threadIdx.x;
    int gid = blockIdx.x * 256 + tid;
    int v = (gid < N) ? cnt[gid] : 0;
    s[tid] = v;
    __syncthreads();
    for (int off = 1; off < 256; off <<= 1) {
        int t = (tid >= off) ? s[tid - off] : 0;
        __syncthreads();
        s[tid] += t;
        __syncthreads();
    }
    if (gid < N) row_ptr[gid] = s[tid] - v;   // local exclusive
    if (tid == 255) bsum[blockIdx.x] = s[255];
}

__global__ void scan_top(int* __restrict__ bsum, int nb) {
    __shared__ int s[512];
    int tid = threadIdx.x;
    int v = (tid < nb) ? bsum[tid] : 0;
    s[tid] = v;
    __syncthreads();
    for (int off = 1; off < 512; off <<= 1) {
        int t = (tid >= off) ? s[tid - off] : 0;
        __syncthreads();
        s[tid] += t;
        __syncthreads();
    }
    if (tid < nb) bsum[tid] = s[tid] - v;     // exclusive
}

__global__ void scan_add(int* __restrict__ row_ptr, const int* __restrict__ bsum,
                         int N, int E) {
    int gid = blockIdx.x * 256 + threadIdx.x;
    if (gid < N) row_ptr[gid] += bsum[blockIdx.x];
    if (gid == 0) row_ptr[N] = E;
}

__global__ void fill_csr(const int* __restrict__ src, const int* __restrict__ dst,
                         const int* __restrict__ row_ptr, int* __restrict__ fill,
                         int* __restrict__ col, int E) {
    int e = blockIdx.x * blockDim.x + threadIdx.x;
    if (e < E) {
        int d = dst[e];
        int p = atomicAdd(&fill[d], 1);
        col[row_ptr[d] + p] = src[e];
    }
}

// ---------------- weight pre-swizzle (frag-major bf16) ----------------
// A-operand layout for mfma_16x16x32: lane l holds A[row=l&15][k=(l>>4)*8+j].
// GEMM1 computes hidT = W1T @ AhT: A = W1T -> elem = W1[k][row], W1 is [IN][HID].
// W1s[((rf*4+kf)*64 + l)*8 + j]

__global__ void pack_w1(const float* __restrict__ W1, short* __restrict__ W1s) {
    int i = blockIdx.x * 256 + threadIdx.x;
    if (i >= 16 * 4 * 64 * 8) return;
    int j = i & 7, l = (i >> 3) & 63, kf = (i >> 9) & 3, rf = i >> 11;
    int k = kf * 32 + (l >> 4) * 8 + j;   // in-feat  0..127
    int r = rf * 16 + (l & 15);           // hid-feat 0..255
    W1s[i] = (short)f2bf(W1[(size_t)k * HID_DIM + r]);
}

// GEMM2: outT = W2T @ hidT: A = W2T -> elem = W2[k][row], W2 is [HID][OUT].
// W2s[((rf*8+kf)*64 + l)*8 + j]
__global__ void pack_w2(const float* __restrict__ W2, short* __restrict__ W2s) {
    int i = blockIdx.x * 256 + threadIdx.x;
    if (i >= 8 * 8 * 64 * 8) return;
    int j = i & 7, l = (i >> 3) & 63, kf = (i >> 9) & 7, rf = i >> 12;
    int k = kf * 32 + (l >> 4) * 8 + j;   // hid-feat 0..255
    int r = rf * 16 + (l & 15);           // out-feat 0..127
    W2s[i] = (short)f2bf(W2[(size_t)k * OUT_DIM + r]);
}

// ---------------- propagation ----------------
// State lives ONLY as packed bf16 pairs: sh[node*64 + l] = (g[2l], g[2l+1]).
// ffeat[node*64 + l] = packed bf16 of 0.1*norm*feat (the per-hop additive term).

__global__ void init_g(const float* __restrict__ feat, const float* __restrict__ norm,
                       unsigned int* __restrict__ sh, unsigned int* __restrict__ ffeat,
                       int N) {
    int idx = blockIdx.x * blockDim.x + threadIdx.x;   // one bf16-pair per thread
    int total = N * 64;
    if (idx >= total) return;
    int row = idx >> 6;
    int l   = idx & 63;
    float nr = norm[row];
    float2 f = *(const float2*)(feat + (size_t)row * IN_DIM + l * 2);
    sh[idx]    = pack_bf2(nr * f.x, nr * f.y);
    ffeat[idx] = pack_bf2(0.1f * nr * f.x, 0.1f * nr * f.y);
}

// one full wave per dst node; lane owns dims (2l, 2l+1) as one packed uint.
// sh_out[d] = bf16( 0.9*norm[d]^2 * (sh_in[d] + sum_{s in N(d)} sh_in[s]) + ffeat[d] )
__global__ __launch_bounds__(256) void hop_kernel(
    const unsigned int* __restrict__ sh_in, unsigned int* __restrict__ sh_out,
    const unsigned int* __restrict__ ffeat, const float* __restrict__ norm,
    const int* __restrict__ row_ptr, const int* __restrict__ col,
    int N) {
    int node = __builtin_amdgcn_readfirstlane(blockIdx.x * 4 + (threadIdx.x >> 6));
    int lane = threadIdx.x & 63;
    if (node >= N) return;
    size_t base = (size_t)node * 64 + lane;
    unsigned int uself = sh_in[base];
    float2 acc = { bf_lo(uself), bf_hi(uself) };       // self loop
    int beg = row_ptr[node], end = row_ptr[node + 1];  // scalar loads
    int e = beg;
    for (; e + 7 < end; e += 8) {
        int s0 = col[e],     s1 = col[e + 1], s2 = col[e + 2], s3 = col[e + 3];
        int s4 = col[e + 4], s5 = col[e + 5], s6 = col[e + 6], s7 = col[e + 7];
        unsigned int u0 = sh_in[(size_t)s0 * 64 + lane];
        unsigned int u1 = sh_in[(size_t)s1 * 64 + lane];
        unsigned int u2 = sh_in[(size_t)s2 * 64 + lane];
        unsigned int u3 = sh_in[(size_t)s3 * 64 + lane];
        unsigned int u4 = sh_in[(size_t)s4 * 64 + lane];
        unsigned int u5 = sh_in[(size_t)s5 * 64 + lane];
        unsigned int u6 = sh_in[(size_t)s6 * 64 + lane];
        unsigned int u7 = sh_in[(size_t)s7 * 64 + lane];
        acc.x += (bf_lo(u0) + bf_lo(u1)) + (bf_lo(u2) + bf_lo(u3))
               + (bf_lo(u4) + bf_lo(u5)) + (bf_lo(u6) + bf_lo(u7));
        acc.y += (bf_hi(u0) + bf_hi(u1)) + (bf_hi(u2) + bf_hi(u3))
               + (bf_hi(u4) + bf_hi(u5)) + (bf_hi(u6) + bf_hi(u7));
    }
    for (; e < end; ++e) {
        unsigned int u = sh_in[(size_t)col[e] * 64 + lane];
        acc.x += bf_lo(u);
        acc.y += bf_hi(u);
    }
    float nr = norm[node];
    float c1 = 0.9f * nr * nr;
    unsigned int uff = ffeat[base];
    float ox = c1 * acc.x + bf_lo(uff);
    float oy = c1 * acc.y + bf_hi(uff);
    sh_out[base] = pack_bf2(ox, oy);
}

// ---------------- fused MLP via bf16 MFMA ----------------
// Computes transposed: hidT = W1T@AhT, outT = W2T@hidT so that node-major
// LDS tiles are the B operands (contiguous b128 frag reads) and D-frags give
// 4 consecutive FEATURES per lane (b64 LDS writes / float4 global stores).
// 64 nodes per block, 4 waves.

#define LDA 136   // Ah row stride (bf16), 272B = 68 words -> 2-way banks
#define LDH 264   // Hid row stride (bf16), 528B = 132 words -> 2-way banks

__global__ __launch_bounds__(256) void mlp_mfma(
    const unsigned int* __restrict__ sh, const float* __restrict__ norm,
    const short* __restrict__ W1s, const float* __restrict__ b1,
    const short* __restrict__ W2s, const float* __restrict__ b2,
    float* __restrict__ out, int N)
{
    __shared__ short Ah[64 * LDA];    // 17408 B, h = unpack(sh)/norm, bf16
    __shared__ short Hid[64 * LDH];   // 33792 B, relu(h@W1+b1), bf16
    int tid  = threadIdx.x;
    int wid  = tid >> 6;
    int lane = tid & 63;
    int row0 = blockIdx.x * 64;

    // ---- stage Ah (64 rows x 64 packed uints) ----
    for (int i = tid; i < 64 * 64; i += 256) {
        int r = i >> 6, c = i & 63;
        int row = row0 + r;
        unsigned int u = 0;
        float inv = 1.f;
        if (row < N) { u = sh[(size_t)row * 64 + c]; inv = 1.0f / norm[row]; }
        *(unsigned int*)&Ah[r * LDA + c * 2] = pack_bf2(bf_lo(u) * inv, bf_hi(u) * inv);
    }
    __syncthreads();

    int m = lane & 15;        // node-in-frag / feat row lane
    int g = lane >> 4;        // k-group

    // ---- GEMM1: wave w -> hid feats [w*64, w*64+64), all 64 nodes ----
    {
        bf16x8 Bf[4][4];      // [kf][cf] from Ah
        #pragma unroll
        for (int kf = 0; kf < 4; ++kf)
            #pragma unroll
            for (int cf = 0; cf < 4; ++cf)
                Bf[kf][cf] = *(const bf16x8*)&Ah[(cf * 16 + m) * LDA + kf * 32 + g * 8];

        f32x4 acc[4][4];      // [rf_local][cf]
        #pragma unroll
        for (int i = 0; i < 4; ++i)
            #pragma unroll
            for (int cf = 0; cf < 4; ++cf)
                acc[i][cf] = (f32x4){0.f, 0.f, 0.f, 0.f};

        #pragma unroll
        for (int i = 0; i < 4; ++i) {
            int rf = wid * 4 + i;
            #pragma unroll
            for (int kf = 0; kf < 4; ++kf) {
                bf16x8 Af = *(const bf16x8*)(W1s + (((size_t)(rf * 4 + kf)) * 64 + lane) * 8);
                #pragma unroll
                for (int cf = 0; cf < 4; ++cf)
                    acc[i][cf] = __builtin_amdgcn_mfma_f32_16x16x32_bf16(
                        Af, Bf[kf][cf], acc[i][cf], 0, 0, 0);
            }
        }

        // bias + relu + bf16 -> Hid LDS (4 consecutive feats per lane)
        #pragma unroll
        for (int i = 0; i < 4; ++i) {
            int feat0 = (wid * 4 + i) * 16 + g * 4;
            float4 bias = *(const float4*)(b1 + feat0);
            #pragma unroll
            for (int cf = 0; cf < 4; ++cf) {
                int node = cf * 16 + m;
                float v0 = acc[i][cf][0] + bias.x; v0 = v0 > 0.f ? v0 : 0.f;
                float v1 = acc[i][cf][1] + bias.y; v1 = v1 > 0.f ? v1 : 0.f;
                float v2 = acc[i][cf][2] + bias.z; v2 = v2 > 0.f ? v2 : 0.f;
                float v3 = acc[i][cf][3] + bias.w; v3 = v3 > 0.f ? v3 : 0.f;
                uint2 p;
                p.x = pack_bf2(v0, v1);
                p.y = pack_bf2(v2, v3);
                *(uint2*)&Hid[node * LDH + feat0] = p;   // ds_write_b64
            }
        }
    }
    __syncthreads();

    // ---- GEMM2: wave w -> out feats [w*32, w*32+32), all 64 nodes ----
    {
        f32x4 acc2[2][4];
        #pragma unroll
        for (int i = 0; i < 2; ++i)
            #pragma unroll
            for (int cf = 0; cf < 4; ++cf)
                acc2[i][cf] = (f32x4){0.f, 0.f, 0.f, 0.f};

        #pragma unroll
        for (int kf = 0; kf < 8; ++kf) {
            bf16x8 Bh[4];
            #pragma unroll
            for (int cf = 0; cf < 4; ++cf)
                Bh[cf] = *(const bf16x8*)&Hid[(cf * 16 + m) * LDH + kf * 32 + g * 8];
            #pragma unroll
            for (int i = 0; i < 2; ++i) {
                int rf = wid * 2 + i;
                bf16x8 Af = *(const bf16x8*)(W2s + (((size_t)(rf * 8 + kf)) * 64 + lane) * 8);
                #pragma unroll
                for (int cf = 0; cf < 4; ++cf)
                    acc2[i][cf] = __builtin_amdgcn_mfma_f32_16x16x32_bf16(
                        Af, Bh[cf], acc2[i][cf], 0, 0, 0);
            }
        }

        #pragma unroll
        for (int i = 0; i < 2; ++i) {
            int feat0 = (wid * 2 + i) * 16 + g * 4;
            float4 bias = *(const float4*)(b2 + feat0);
            #pragma unroll
            for (int cf = 0; cf < 4; ++cf) {
                int node = row0 + cf * 16 + m;
                if (node < N) {
                    float4 o;
                    o.x = acc2[i][cf][0] + bias.x;
                    o.y = acc2[i][cf][1] + bias.y;
                    o.z = acc2[i][cf][2] + bias.z;
                    o.w = acc2[i][cf][3] + bias.w;
                    *(float4*)(out + (size_t)node * OUT_DIM + feat0) = o;
                }
            }
        }
    }
}

// ---------------- launch ----------------

extern "C" void kernel_launch(void* const* d_in, const int* in_sizes, int n_in,
                              void* d_out, int out_size, void* d_ws, size_t ws_size,
                              hipStream_t stream) {
    const float* feat = (const float*)d_in[0];
    const float* W1   = (const float*)d_in[1];
    const float* b1   = (const float*)d_in[2];
    const float* W2   = (const float*)d_in[3];
    const float* b2   = (const float*)d_in[4];
    const int*   src  = (const int*)d_in[5];
    const int*   dst  = (const int*)d_in[6];
    float* out = (float*)d_out;

    int N = in_sizes[0] / IN_DIM;     // 100000
    int E = in_sizes[5];              // 1600000

    // workspace carve (256B aligned)
    size_t off = 0;
    auto carve = [&](size_t bytes) -> void* {
        void* p = (char*)d_ws + off;
        off += (bytes + 255) & ~(size_t)255;
        return p;
    };
    float* norm    = (float*)carve((size_t)N * 4);
    int*   cnt     = (int*)carve((size_t)N * 4);
    int*   row_ptr = (int*)carve((size_t)(N + 1) * 4);
    int*   fill    = (int*)carve((size_t)N * 4);
    int*   bsum    = (int*)carve(512 * 4);
    int*   col     = (int*)carve((size_t)E * 4);
    unsigned int* shA   = (unsigned int*)carve((size_t)N * 64 * 4);  // bf16 state ping
    unsigned int* shB   = (unsigned int*)carve((size_t)N * 64 * 4);  // bf16 state pong
    unsigned int* ffeat = (unsigned int*)carve((size_t)N * 64 * 4);  // bf16 0.1*norm*feat
    short* W1s = (short*)carve((size_t)16 * 4 * 64 * 8 * 2);         // 64KB frag-major
    short* W2s = (short*)carve((size_t)8 * 8 * 64 * 8 * 2);          // 128KB frag-major
    (void)ws_size;

    int nbN = (N + 255) / 256;        // 391
    int nbE = (E + 255) / 256;        // 6250

    count_init<<<nbN, 256, 0, stream>>>(cnt, fill, N);
    count_edges<<<nbE, 256, 0, stream>>>(dst, cnt, E);
    norm_kernel<<<nbN, 256, 0, stream>>>(cnt, norm, N);
    scan_block<<<nbN, 256, 0, stream>>>(cnt, row_ptr, bsum, N);
    scan_top<<<1, 512, 0, stream>>>(bsum, nbN);
    scan_add<<<nbN, 256, 0, stream>>>(row_ptr, bsum, N, E);
    fill_csr<<<nbE, 256, 0, stream>>>(src, dst, row_ptr, fill, col, E);

    pack_w1<<<128, 256, 0, stream>>>(W1, W1s);
    pack_w2<<<256, 256, 0, stream>>>(W2, W2s);

    int nbG = ((size_t)N * 64 + 255) / 256;
    init_g<<<nbG, 256, 0, stream>>>(feat, norm, shA, ffeat, N);

    // one wave per node, 4 nodes per block
    int nbHop = (N + 3) / 4;
    for (int t = 0; t < KHOPS; ++t) {
        const unsigned int* si = (t % 2 == 0) ? shA : shB;
        unsigned int*       so = (t % 2 == 0) ? shB : shA;
        hop_kernel<<<nbHop, 256, 0, stream>>>(si, so, ffeat, norm, row_ptr, col, N);
    }
    // after 10 hops (even count), final state is in shA

    int nbM = (N + 63) / 64;
    mlp_mfma<<<nbM, 256, 0, stream>>>(shA, norm, W1s, b1, W2s, b2, out, N);
}

// Round 8
// 859.576 us; speedup vs baseline: 2.1467x; 1.0304x over previous
//
#include <hip/hip_runtime.h>

#define IN_DIM 128
#define HID_DIM 256
#define OUT_DIM 128
#define KHOPS 10

#define NBUCK 32      // dst>>12 -> buckets 0..24 used (4096 nodes each)
#define NBLK_B 640    // blocks for bucket passes (must match count/fill)

typedef __attribute__((ext_vector_type(8))) short bf16x8;
typedef __attribute__((ext_vector_type(4))) float f32x4;

// bf16 round-to-nearest-even from fp32
__device__ __forceinline__ unsigned short f2bf(float x) {
    unsigned int b = __float_as_uint(x);
    unsigned int r = (b + 0x7FFFu + ((b >> 16) & 1u)) >> 16;
    return (unsigned short)r;
}
__device__ __forceinline__ unsigned int pack_bf2(float lo, float hi) {
    return (unsigned int)f2bf(lo) | ((unsigned int)f2bf(hi) << 16);
}
__device__ __forceinline__ float bf_lo(unsigned int u) { return __uint_as_float(u << 16); }
__device__ __forceinline__ float bf_hi(unsigned int u) { return __uint_as_float(u & 0xFFFF0000u); }

// ---------------- CSR build (dst-bucketed to kill scatter write-amp) ----------------

__global__ void count_init(int* __restrict__ cnt, int* __restrict__ fill,
                           int* __restrict__ bucket_cnt, int N) {
    int i = blockIdx.x * blockDim.x + threadIdx.x;
    if (i < N) { cnt[i] = 0; fill[i] = 0; }
    if (i < NBUCK) bucket_cnt[i] = 0;
}

// pass A1: per-block bucket histogram; reserve per-block ranges via one atomic per bucket
__global__ __launch_bounds__(256) void bucket_count(
    const int* __restrict__ dst, int* __restrict__ bucket_cnt,
    int* __restrict__ blk_base, int E) {
    __shared__ int h[NBUCK];
    int tid = threadIdx.x;
    if (tid < NBUCK) h[tid] = 0;
    __syncthreads();
    for (int e = blockIdx.x * 256 + tid; e < E; e += NBLK_B * 256)
        atomicAdd(&h[dst[e] >> 12], 1);
    __syncthreads();
    if (tid < NBUCK)
        blk_base[blockIdx.x * NBUCK + tid] = atomicAdd(&bucket_cnt[tid], h[tid]);
}

// pass A2: exclusive scan of the 32 bucket counts
__global__ void bucket_scan(const int* __restrict__ bucket_cnt,
                            int* __restrict__ bucket_start) {
    __shared__ int s[NBUCK];
    int tid = threadIdx.x;   // 32 threads
    int v = bucket_cnt[tid];
    s[tid] = v;
    __syncthreads();
    for (int off = 1; off < NBUCK; off <<= 1) {
        int t = (tid >= off) ? s[tid - off] : 0;
        __syncthreads();
        s[tid] += t;
        __syncthreads();
    }
    bucket_start[tid] = s[tid] - v;
}

// pass A3: write (src,dst) pairs into bucket-ordered array
__global__ __launch_bounds__(256) void bucket_fill(
    const int* __restrict__ src, const int* __restrict__ dst,
    const int* __restrict__ bucket_start, const int* __restrict__ blk_base,
    uint2* __restrict__ pairs, int E) {
    __shared__ int base[NBUCK];
    int tid = threadIdx.x;
    if (tid < NBUCK) base[tid] = bucket_start[tid] + blk_base[blockIdx.x * NBUCK + tid];
    __syncthreads();
    for (int e = blockIdx.x * 256 + tid; e < E; e += NBLK_B * 256) {
        int d = dst[e], s = src[e];
        int p = atomicAdd(&base[d >> 12], 1);
        pairs[p] = make_uint2((unsigned)s, (unsigned)d);
    }
}

// pass B1: count in-degrees from bucket-ordered pairs (atomics confined to 16KB windows)
__global__ void count_pairs(const uint2* __restrict__ pairs, int* __restrict__ cnt, int E) {
    int e = blockIdx.x * blockDim.x + threadIdx.x;
    if (e < E) atomicAdd(&cnt[pairs[e].y], 1);
}

__global__ void norm_kernel(const int* __restrict__ cnt, float* __restrict__ norm, int N) {
    int i = blockIdx.x * blockDim.x + threadIdx.x;
    if (i < N) {
        float deg = (float)(cnt[i] + 1);   // +1 self loop, always >= 1
        norm[i] = rsqrtf(deg);
    }
}

__global__ void scan_block(const int* __restrict__ cnt, int* __restrict__ row_ptr,
                           int* __restrict__ bsum, int N) {
    __shared__ int s[256];
    int tid = threadIdx.x;
    int gid = blockIdx.x * 256 + tid;
    int v = (gid < N) ? cnt[gid] : 0;
    s[tid] = v;
    __syncthreads();
    for (int off = 1; off < 256; off <<= 1) {
        int t = (tid >= off) ? s[tid - off] : 0;
        __syncthreads();
        s[tid] += t;
        __syncthreads();
    }
    if (gid < N) row_ptr[gid] = s[tid] - v;   // local exclusive
    if (tid == 255) bsum[blockIdx.x] = s[255];
}

__global__ void scan_top(int* __restrict__ bsum, int nb) {
    __shared__ int s[512];
    int tid = threadIdx.x;
    int v = (tid < nb) ? bsum[tid] : 0;
    s[tid] = v;
    __syncthreads();
    for (int off = 1; off < 512; off <<= 1) {
        int t = (tid >= off) ? s[tid - off] : 0;
        __syncthreads();
        s[tid] += t;
        __syncthreads();
    }
    if (tid < nb) bsum[tid] = s[tid] - v;     // exclusive
}

__global__ void scan_add(int* __restrict__ row_ptr, const int* __restrict__ bsum,
                         int N, int E) {
    int gid = blockIdx.x * 256 + threadIdx.x;
    if (gid < N) row_ptr[gid] += bsum[blockIdx.x];
    if (gid == 0) row_ptr[N] = E;
}

// pass B2: fill CSR col from bucket-ordered pairs (scatter confined to ~260KB windows)
__global__ void fill_pairs(const uint2* __restrict__ pairs, const int* __restrict__ row_ptr,
                           int* __restrict__ fill, int* __restrict__ col, int E) {
    int e = blockIdx.x * blockDim.x + threadIdx.x;
    if (e < E) {
        uint2 pr = pairs[e];
        int p = atomicAdd(&fill[pr.y], 1);
        col[row_ptr[pr.y] + p] = (int)pr.x;
    }
}

// ---------------- weight pre-swizzle (frag-major bf16) ----------------

__global__ void pack_w1(const float* __restrict__ W1, short* __restrict__ W1s) {
    int i = blockIdx.x * 256 + threadIdx.x;
    if (i >= 16 * 4 * 64 * 8) return;
    int j = i & 7, l = (i >> 3) & 63, kf = (i >> 9) & 3, rf = i >> 11;
    int k = kf * 32 + (l >> 4) * 8 + j;   // in-feat  0..127
    int r = rf * 16 + (l & 15);           // hid-feat 0..255
    W1s[i] = (short)f2bf(W1[(size_t)k * HID_DIM + r]);
}

__global__ void pack_w2(const float* __restrict__ W2, short* __restrict__ W2s) {
    int i = blockIdx.x * 256 + threadIdx.x;
    if (i >= 8 * 8 * 64 * 8) return;
    int j = i & 7, l = (i >> 3) & 63, kf = (i >> 9) & 7, rf = i >> 12;
    int k = kf * 32 + (l >> 4) * 8 + j;   // hid-feat 0..255
    int r = rf * 16 + (l & 15);           // out-feat 0..127
    W2s[i] = (short)f2bf(W2[(size_t)k * OUT_DIM + r]);
}

// ---------------- propagation ----------------
// State lives ONLY as packed bf16 pairs: sh[node*64 + l] = (g[2l], g[2l+1]).
// ffeat[node*64 + l] = packed bf16 of 0.1*norm*feat (the per-hop additive term).

__global__ void init_g(const float* __restrict__ feat, const float* __restrict__ norm,
                       unsigned int* __restrict__ sh, unsigned int* __restrict__ ffeat,
                       int N) {
    int idx = blockIdx.x * blockDim.x + threadIdx.x;   // one bf16-pair per thread
    int total = N * 64;
    if (idx >= total) return;
    int row = idx >> 6;
    int l   = idx & 63;
    float nr = norm[row];
    float2 f = *(const float2*)(feat + (size_t)row * IN_DIM + l * 2);
    sh[idx]    = pack_bf2(nr * f.x, nr * f.y);
    ffeat[idx] = pack_bf2(0.1f * nr * f.x, 0.1f * nr * f.y);
}

// one full wave per dst node; lane owns dims (2l, 2l+1) as one packed uint.
// sh_out[d] = bf16( 0.9*norm[d]^2 * (sh_in[d] + sum_{s in N(d)} sh_in[s]) + ffeat[d] )
__global__ __launch_bounds__(256) void hop_kernel(
    const unsigned int* __restrict__ sh_in, unsigned int* __restrict__ sh_out,
    const unsigned int* __restrict__ ffeat, const float* __restrict__ norm,
    const int* __restrict__ row_ptr, const int* __restrict__ col,
    int N) {
    int node = __builtin_amdgcn_readfirstlane(blockIdx.x * 4 + (threadIdx.x >> 6));
    int lane = threadIdx.x & 63;
    if (node >= N) return;
    size_t base = (size_t)node * 64 + lane;
    unsigned int uself = sh_in[base];
    float2 acc = { bf_lo(uself), bf_hi(uself) };       // self loop
    int beg = row_ptr[node], end = row_ptr[node + 1];  // scalar loads
    int e = beg;
    for (; e + 7 < end; e += 8) {
        int s0 = col[e],     s1 = col[e + 1], s2 = col[e + 2], s3 = col[e + 3];
        int s4 = col[e + 4], s5 = col[e + 5], s6 = col[e + 6], s7 = col[e + 7];
        unsigned int u0 = sh_in[(size_t)s0 * 64 + lane];
        unsigned int u1 = sh_in[(size_t)s1 * 64 + lane];
        unsigned int u2 = sh_in[(size_t)s2 * 64 + lane];
        unsigned int u3 = sh_in[(size_t)s3 * 64 + lane];
        unsigned int u4 = sh_in[(size_t)s4 * 64 + lane];
        unsigned int u5 = sh_in[(size_t)s5 * 64 + lane];
        unsigned int u6 = sh_in[(size_t)s6 * 64 + lane];
        unsigned int u7 = sh_in[(size_t)s7 * 64 + lane];
        acc.x += (bf_lo(u0) + bf_lo(u1)) + (bf_lo(u2) + bf_lo(u3))
               + (bf_lo(u4) + bf_lo(u5)) + (bf_lo(u6) + bf_lo(u7));
        acc.y += (bf_hi(u0) + bf_hi(u1)) + (bf_hi(u2) + bf_hi(u3))
               + (bf_hi(u4) + bf_hi(u5)) + (bf_hi(u6) + bf_hi(u7));
    }
    for (; e < end; ++e) {
        unsigned int u = sh_in[(size_t)col[e] * 64 + lane];
        acc.x += bf_lo(u);
        acc.y += bf_hi(u);
    }
    float nr = norm[node];
    float c1 = 0.9f * nr * nr;
    unsigned int uff = ffeat[base];
    float ox = c1 * acc.x + bf_lo(uff);
    float oy = c1 * acc.y + bf_hi(uff);
    sh_out[base] = pack_bf2(ox, oy);
}

// ---------------- fused MLP via bf16 MFMA ----------------
// Computes transposed: hidT = W1T@AhT, outT = W2T@hidT. 64 nodes/block, 4 waves.

#define LDA 136   // Ah row stride (bf16)
#define LDH 264   // Hid row stride (bf16)

__global__ __launch_bounds__(256) void mlp_mfma(
    const unsigned int* __restrict__ sh, const float* __restrict__ norm,
    const short* __restrict__ W1s, const float* __restrict__ b1,
    const short* __restrict__ W2s, const float* __restrict__ b2,
    float* __restrict__ out, int N)
{
    __shared__ short Ah[64 * LDA];    // 17408 B, h = unpack(sh)/norm, bf16
    __shared__ short Hid[64 * LDH];   // 33792 B, relu(h@W1+b1), bf16
    int tid  = threadIdx.x;
    int wid  = tid >> 6;
    int lane = tid & 63;
    int row0 = blockIdx.x * 64;

    // ---- stage Ah (64 rows x 64 packed uints) ----
    for (int i = tid; i < 64 * 64; i += 256) {
        int r = i >> 6, c = i & 63;
        int row = row0 + r;
        unsigned int u = 0;
        float inv = 1.f;
        if (row < N) { u = sh[(size_t)row * 64 + c]; inv = 1.0f / norm[row]; }
        *(unsigned int*)&Ah[r * LDA + c * 2] = pack_bf2(bf_lo(u) * inv, bf_hi(u) * inv);
    }
    __syncthreads();

    int m = lane & 15;        // node-in-frag / feat row lane
    int g = lane >> 4;        // k-group

    // ---- GEMM1: wave w -> hid feats [w*64, w*64+64), all 64 nodes ----
    {
        bf16x8 Bf[4][4];      // [kf][cf] from Ah
        #pragma unroll
        for (int kf = 0; kf < 4; ++kf)
            #pragma unroll
            for (int cf = 0; cf < 4; ++cf)
                Bf[kf][cf] = *(const bf16x8*)&Ah[(cf * 16 + m) * LDA + kf * 32 + g * 8];

        f32x4 acc[4][4];      // [rf_local][cf]
        #pragma unroll
        for (int i = 0; i < 4; ++i)
            #pragma unroll
            for (int cf = 0; cf < 4; ++cf)
                acc[i][cf] = (f32x4){0.f, 0.f, 0.f, 0.f};

        #pragma unroll
        for (int i = 0; i < 4; ++i) {
            int rf = wid * 4 + i;
            #pragma unroll
            for (int kf = 0; kf < 4; ++kf) {
                bf16x8 Af = *(const bf16x8*)(W1s + (((size_t)(rf * 4 + kf)) * 64 + lane) * 8);
                #pragma unroll
                for (int cf = 0; cf < 4; ++cf)
                    acc[i][cf] = __builtin_amdgcn_mfma_f32_16x16x32_bf16(
                        Af, Bf[kf][cf], acc[i][cf], 0, 0, 0);
            }
        }

        // bias + relu + bf16 -> Hid LDS (4 consecutive feats per lane)
        #pragma unroll
        for (int i = 0; i < 4; ++i) {
            int feat0 = (wid * 4 + i) * 16 + g * 4;
            float4 bias = *(const float4*)(b1 + feat0);
            #pragma unroll
            for (int cf = 0; cf < 4; ++cf) {
                int node = cf * 16 + m;
                float v0 = acc[i][cf][0] + bias.x; v0 = v0 > 0.f ? v0 : 0.f;
                float v1 = acc[i][cf][1] + bias.y; v1 = v1 > 0.f ? v1 : 0.f;
                float v2 = acc[i][cf][2] + bias.z; v2 = v2 > 0.f ? v2 : 0.f;
                float v3 = acc[i][cf][3] + bias.w; v3 = v3 > 0.f ? v3 : 0.f;
                uint2 p;
                p.x = pack_bf2(v0, v1);
                p.y = pack_bf2(v2, v3);
                *(uint2*)&Hid[node * LDH + feat0] = p;   // ds_write_b64
            }
        }
    }
    __syncthreads();

    // ---- GEMM2: wave w -> out feats [w*32, w*32+32), all 64 nodes ----
    {
        f32x4 acc2[2][4];
        #pragma unroll
        for (int i = 0; i < 2; ++i)
            #pragma unroll
            for (int cf = 0; cf < 4; ++cf)
                acc2[i][cf] = (f32x4){0.f, 0.f, 0.f, 0.f};

        #pragma unroll
        for (int kf = 0; kf < 8; ++kf) {
            bf16x8 Bh[4];
            #pragma unroll
            for (int cf = 0; cf < 4; ++cf)
                Bh[cf] = *(const bf16x8*)&Hid[(cf * 16 + m) * LDH + kf * 32 + g * 8];
            #pragma unroll
            for (int i = 0; i < 2; ++i) {
                int rf = wid * 2 + i;
                bf16x8 Af = *(const bf16x8*)(W2s + (((size_t)(rf * 8 + kf)) * 64 + lane) * 8);
                #pragma unroll
                for (int cf = 0; cf < 4; ++cf)
                    acc2[i][cf] = __builtin_amdgcn_mfma_f32_16x16x32_bf16(
                        Af, Bh[cf], acc2[i][cf], 0, 0, 0);
            }
        }

        #pragma unroll
        for (int i = 0; i < 2; ++i) {
            int feat0 = (wid * 2 + i) * 16 + g * 4;
            float4 bias = *(const float4*)(b2 + feat0);
            #pragma unroll
            for (int cf = 0; cf < 4; ++cf) {
                int node = row0 + cf * 16 + m;
                if (node < N) {
                    float4 o;
                    o.x = acc2[i][cf][0] + bias.x;
                    o.y = acc2[i][cf][1] + bias.y;
                    o.z = acc2[i][cf][2] + bias.z;
                    o.w = acc2[i][cf][3] + bias.w;
                    *(float4*)(out + (size_t)node * OUT_DIM + feat0) = o;
                }
            }
        }
    }
}

// ---------------- launch ----------------

extern "C" void kernel_launch(void* const* d_in, const int* in_sizes, int n_in,
                              void* d_out, int out_size, void* d_ws, size_t ws_size,
                              hipStream_t stream) {
    const float* feat = (const float*)d_in[0];
    const float* W1   = (const float*)d_in[1];
    const float* b1   = (const float*)d_in[2];
    const float* W2   = (const float*)d_in[3];
    const float* b2   = (const float*)d_in[4];
    const int*   src  = (const int*)d_in[5];
    const int*   dst  = (const int*)d_in[6];
    float* out = (float*)d_out;

    int N = in_sizes[0] / IN_DIM;     // 100000
    int E = in_sizes[5];              // 1600000

    // workspace carve (256B aligned)
    size_t off = 0;
    auto carve = [&](size_t bytes) -> void* {
        void* p = (char*)d_ws + off;
        off += (bytes + 255) & ~(size_t)255;
        return p;
    };
    float* norm    = (float*)carve((size_t)N * 4);
    int*   cnt     = (int*)carve((size_t)N * 4);
    int*   row_ptr = (int*)carve((size_t)(N + 1) * 4);
    int*   fill    = (int*)carve((size_t)N * 4);
    int*   bsum    = (int*)carve(512 * 4);
    int*   col     = (int*)carve((size_t)E * 4);
    unsigned int* shA   = (unsigned int*)carve((size_t)N * 64 * 4);  // bf16 state ping
    unsigned int* shB   = (unsigned int*)carve((size_t)N * 64 * 4);  // bf16 state pong
    unsigned int* ffeat = (unsigned int*)carve((size_t)N * 64 * 4);  // bf16 0.1*norm*feat
    short* W1s = (short*)carve((size_t)16 * 4 * 64 * 8 * 2);
    short* W2s = (short*)carve((size_t)8 * 8 * 64 * 8 * 2);
    int*   bucket_cnt   = (int*)carve(NBUCK * 4);
    int*   bucket_start = (int*)carve(NBUCK * 4);
    int*   blk_base     = (int*)carve((size_t)NBLK_B * NBUCK * 4);
    uint2* pairs        = (uint2*)carve((size_t)E * 8);
    (void)ws_size;

    int nbN = (N + 255) / 256;        // 391
    int nbE = (E + 255) / 256;        // 6250

    count_init<<<nbN, 256, 0, stream>>>(cnt, fill, bucket_cnt, N);
    bucket_count<<<NBLK_B, 256, 0, stream>>>(dst, bucket_cnt, blk_base, E);
    bucket_scan<<<1, NBUCK, 0, stream>>>(bucket_cnt, bucket_start);
    bucket_fill<<<NBLK_B, 256, 0, stream>>>(src, dst, bucket_start, blk_base, pairs, E);
    count_pairs<<<nbE, 256, 0, stream>>>(pairs, cnt, E);
    norm_kernel<<<nbN, 256, 0, stream>>>(cnt, norm, N);
    scan_block<<<nbN, 256, 0, stream>>>(cnt, row_ptr, bsum, N);
    scan_top<<<1, 512, 0, stream>>>(bsum, nbN);
    scan_add<<<nbN, 256, 0, stream>>>(row_ptr, bsum, N, E);
    fill_pairs<<<nbE, 256, 0, stream>>>(pairs, row_ptr, fill, col, E);

    pack_w1<<<128, 256, 0, stream>>>(W1, W1s);
    pack_w2<<<256, 256, 0, stream>>>(W2, W2s);

    int nbG = ((size_t)N * 64 + 255) / 256;
    init_g<<<nbG, 256, 0, stream>>>(feat, norm, shA, ffeat, N);

    // one wave per node, 4 nodes per block
    int nbHop = (N + 3) / 4;
    for (int t = 0; t < KHOPS; ++t) {
        const unsigned int* si = (t % 2 == 0) ? shA : shB;
        unsigned int*       so = (t % 2 == 0) ? shB : shA;
        hop_kernel<<<nbHop, 256, 0, stream>>>(si, so, ffeat, norm, row_ptr, col, N);
    }
    // after 10 hops (even count), final state is in shA

    int nbM = (N + 63) / 64;
    mlp_mfma<<<nbM, 256, 0, stream>>>(shA, norm, W1s, b1, W2s, b2, out, N);
}